// Round 4
// baseline (715.476 us; speedup 1.0000x reference)
//
#include <hip/hip_runtime.h>

// ---------------- problem constants ----------------
#define L_     8838            // LATENT
#define LP_    9216            // padded row length (bytes per u8 array row; floats per LDS vec)
#define MPOW   9               // highest kept power of G (tail ~8e-4 of peak term)
#define NSLOT  (MPOW + 1)
#define NFULL  3               // passes 1..NFULL read hi+lo; later passes hi-only
#define CT     512             // chain kernel threads (8 waves)
#define CWGRID 512             // chain grids (grid-stride)
#define CWAVES (CWGRID * (CT / 64))   // 4096 waves
#define HPAIRS ((L_ + 1) / 2)         // 4419 row-pairs

// quantization: q16 = clamp(rn((g + BOFF)/D16), 0, 65535), g = q16*D16 - BOFF
// hi = rn(q16/256) (unbiased hi-only recon), lo = q16 - 256*hi + 128
#define BOFF 6.0e-4f
#define D16  (BOFF / 32768.0f)         // exact power-of-2 relation -> pad recon == 0
#define DHI  (BOFF / 128.0f)           // 256 * D16
#define C2   (BOFF + 128.0f * D16)     // full-recon offset
#define QS   (32768.0f / BOFF)         // 1/D16

typedef float        f32x4 __attribute__((ext_vector_type(4)));
typedef unsigned int u32x4 __attribute__((ext_vector_type(4)));
typedef float        f2v   __attribute__((ext_vector_type(2)));

__device__ __forceinline__ float ubf(unsigned int u, int b) {
    return (float)((u >> (8 * b)) & 255u);   // -> v_cvt_f32_ubyteN
}

// stage fp32 vectors to LDS (73.7 KB total -> 2 blocks/CU)
__device__ __forceinline__ void stage_vec(const float* __restrict__ gin,
                                          const float* __restrict__ hin,
                                          float* sgf, float* shf)
{
    #pragma unroll
    for (int k = 0; k < LP_ / CT; ++k) {   // 18
        const int j = k * CT + threadIdx.x;
        sgf[j] = (j < L_) ? gin[j] : 0.f;
        shf[j] = (j < L_) ? hin[j] : 0.f;
    }
    __syncthreads();
}

// ---------------- full-precision pass (hi+lo, int16 fixed point) ----------------
template<bool PF>
__device__ __forceinline__ void full_row(const float* sgf, const float* shf, int lane,
                                         u32x4 (&mh)[9], u32x4 (&ml)[9],
                                         const unsigned char* RnH, const unsigned char* RnL,
                                         float& ag, float& ah)
{
    #pragma unroll
    for (int c = 0; c < 9; ++c) {
        const f32x4* vgp = (const f32x4*)(sgf + c * 1024 + lane * 16);
        const f32x4* vhp = (const f32x4*)(shf + c * 1024 + lane * 16);
        const u32x4 uh = mh[c], ul = ml[c];
        if constexpr (PF) {                      // prefetch next row into dead regs
            mh[c] = *(const u32x4*)(RnH + c * 1024);
            ml[c] = *(const u32x4*)(RnL + c * 1024);
        }
        #pragma unroll
        for (int d = 0; d < 4; ++d) {
            const f32x4 vg = vgp[d], vh = vhp[d];
            #pragma unroll
            for (int b = 0; b < 4; ++b) {
                const float v = fmaf(ubf(uh[d], b), DHI, fmaf(ubf(ul[d], b), D16, -C2));
                ag = fmaf(v, vg[b], ag);
                ah = fmaf(v, vh[b], ah);
            }
        }
    }
}

__global__ __launch_bounds__(CT)
void chain_full(const unsigned char* __restrict__ GHi, const unsigned char* __restrict__ GLo,
                const float* __restrict__ gin, const float* __restrict__ hin,
                float* __restrict__ gout, float* __restrict__ hout)
{
    __shared__ float sgf[LP_], shf[LP_];
    stage_vec(gin, hin, sgf, shf);
    const int lane = threadIdx.x & 63;
    int row = blockIdx.x * (CT / 64) + (threadIdx.x >> 6);

    u32x4 mh[9], ml[9];
    if (row < L_) {
        const unsigned char* RH = GHi + (size_t)row * LP_ + lane * 16;
        const unsigned char* RL = GLo + (size_t)row * LP_ + lane * 16;
        #pragma unroll
        for (int c = 0; c < 9; ++c) {
            mh[c] = *(const u32x4*)(RH + c * 1024);
            ml[c] = *(const u32x4*)(RL + c * 1024);
        }
    }
    while (row < L_) {
        const int nrow = row + CWAVES;
        const unsigned char* RnH = GHi + (size_t)nrow * LP_ + lane * 16;
        const unsigned char* RnL = GLo + (size_t)nrow * LP_ + lane * 16;
        float ag = 0.f, ah = 0.f;
        if (nrow < L_) full_row<true >(sgf, shf, lane, mh, ml, RnH, RnL, ag, ah);
        else           full_row<false>(sgf, shf, lane, mh, ml, RnH, RnL, ag, ah);
        #pragma unroll
        for (int o = 32; o; o >>= 1) { ag += __shfl_xor(ag, o); ah += __shfl_xor(ah, o); }
        if (lane == 0) { gout[row] = ag; hout[row] = ah; }
        row = nrow;
    }
}

// ---------------- hi-only pass (int8, 81 MB/pass), 2 rows per wave ----------------
__global__ __launch_bounds__(CT)
void chain_hi(const unsigned char* __restrict__ GHi,
              const float* __restrict__ gin, const float* __restrict__ hin,
              float* __restrict__ gout, float* __restrict__ hout)
{
    __shared__ float sgf[LP_], shf[LP_];
    stage_vec(gin, hin, sgf, shf);
    const int lane = threadIdx.x & 63;

    for (int pr = blockIdx.x * (CT / 64) + (threadIdx.x >> 6); pr < HPAIRS; pr += CWAVES) {
        const int r0 = 2 * pr, r1 = r0 + 1;        // L_ even -> r1 always valid
        const unsigned char* R0 = GHi + (size_t)r0 * LP_ + lane * 16;
        const unsigned char* R1 = R0 + LP_;
        u32x4 m0[9], m1[9];
        #pragma unroll
        for (int c = 0; c < 9; ++c) {
            m0[c] = *(const u32x4*)(R0 + c * 1024);
            m1[c] = *(const u32x4*)(R1 + c * 1024);
        }
        float a0g = 0.f, a0h = 0.f, a1g = 0.f, a1h = 0.f;
        #pragma unroll
        for (int c = 0; c < 9; ++c) {
            const f32x4* vgp = (const f32x4*)(sgf + c * 1024 + lane * 16);
            const f32x4* vhp = (const f32x4*)(shf + c * 1024 + lane * 16);
            #pragma unroll
            for (int d = 0; d < 4; ++d) {
                const f32x4 vg = vgp[d], vh = vhp[d];
                #pragma unroll
                for (int b = 0; b < 4; ++b) {
                    const float v0 = fmaf(ubf(m0[c][d], b), DHI, -BOFF);
                    const float v1 = fmaf(ubf(m1[c][d], b), DHI, -BOFF);
                    a0g = fmaf(v0, vg[b], a0g); a0h = fmaf(v0, vh[b], a0h);
                    a1g = fmaf(v1, vg[b], a1g); a1h = fmaf(v1, vh[b], a1h);
                }
            }
        }
        #pragma unroll
        for (int o = 32; o; o >>= 1) {
            a0g += __shfl_xor(a0g, o); a0h += __shfl_xor(a0h, o);
            a1g += __shfl_xor(a1g, o); a1h += __shfl_xor(a1h, o);
        }
        if (lane == 0) {
            gout[r0] = a0g; hout[r0] = a0h;
            gout[r1] = a1g; hout[r1] = a1h;
        }
    }
}

// ---------------- pass 0: fp32 A, exact (A-I)*v, fused hi/lo quantized write ----------------
template<bool WRITE_G>
__global__ __launch_bounds__(CT)
void chain_fp32(const float* __restrict__ A,
                const float* __restrict__ gin, const float* __restrict__ hin,
                unsigned char* __restrict__ GHi, unsigned char* __restrict__ GLo,
                float* __restrict__ gout, float* __restrict__ hout)
{
    __shared__ float sgf[LP_], shf[LP_];
    stage_vec(gin, hin, sgf, shf);
    const int lane = threadIdx.x & 63;

    for (int pr = blockIdx.x * (CT / 64) + (threadIdx.x >> 6); pr < HPAIRS; pr += CWAVES) {
        const int r0 = 2 * pr, r1 = r0 + 1;
        const float* __restrict__ A0 = A + (size_t)r0 * L_;
        const float* __restrict__ A1 = A + (size_t)r1 * L_;

        float a00 = 0.f, a01 = 0.f, a10 = 0.f, a11 = 0.f;
        #pragma unroll 4
        for (int it = 0; it < 36; ++it) {
            const int j0 = it * 256 + lane * 4;
            float x0[4], x1[4];
            if (j0 + 3 < L_) {
                f2v p0 = __builtin_nontemporal_load((const f2v*)(A0 + j0));
                f2v p1 = __builtin_nontemporal_load((const f2v*)(A0 + j0 + 2));
                f2v q0 = __builtin_nontemporal_load((const f2v*)(A1 + j0));
                f2v q1 = __builtin_nontemporal_load((const f2v*)(A1 + j0 + 2));
                x0[0] = p0[0]; x0[1] = p0[1]; x0[2] = p1[0]; x0[3] = p1[1];
                x1[0] = q0[0]; x1[1] = q0[1]; x1[2] = q1[0]; x1[3] = q1[1];
            } else {
                #pragma unroll
                for (int e = 0; e < 4; ++e) {
                    x0[e] = (j0 + e < L_) ? A0[j0 + e] : 0.f;
                    x1[e] = (j0 + e < L_) ? A1[j0 + e] : 0.f;
                }
            }
            if constexpr (WRITE_G) {
                unsigned int hw0 = 0, lw0 = 0, hw1 = 0, lw1 = 0;
                #pragma unroll
                for (int e = 0; e < 4; ++e) {
                    const int j = j0 + e;
                    const float g0 = x0[e] - ((j == r0) ? 1.f : 0.f);
                    const float g1 = x1[e] - ((j == r1) ? 1.f : 0.f);
                    int q0i = __float2int_rn(fmaf(g0, QS, 32768.0f));
                    int q1i = __float2int_rn(fmaf(g1, QS, 32768.0f));
                    q0i = min(max(q0i, 0), 65535); q1i = min(max(q1i, 0), 65535);
                    const int h0 = min((q0i + 128) >> 8, 255);
                    const int h1 = min((q1i + 128) >> 8, 255);
                    const int l0 = min(q0i - (h0 << 8) + 128, 255);
                    const int l1 = min(q1i - (h1 << 8) + 128, 255);
                    hw0 |= (unsigned)h0 << (8 * e); lw0 |= (unsigned)l0 << (8 * e);
                    hw1 |= (unsigned)h1 << (8 * e); lw1 |= (unsigned)l1 << (8 * e);
                }
                *(unsigned int*)(GHi + (size_t)r0 * LP_ + j0) = hw0;
                *(unsigned int*)(GLo + (size_t)r0 * LP_ + j0) = lw0;
                *(unsigned int*)(GHi + (size_t)r1 * LP_ + j0) = hw1;
                *(unsigned int*)(GLo + (size_t)r1 * LP_ + j0) = lw1;
            }
            const f32x4 vg = *(const f32x4*)(sgf + j0);
            const f32x4 vh = *(const f32x4*)(shf + j0);
            #pragma unroll
            for (int e = 0; e < 4; ++e) {
                a00 = fmaf(x0[e], vg[e], a00); a01 = fmaf(x0[e], vh[e], a01);
                a10 = fmaf(x1[e], vg[e], a10); a11 = fmaf(x1[e], vh[e], a11);
            }
        }
        #pragma unroll
        for (int o = 32; o; o >>= 1) {
            a00 += __shfl_xor(a00, o); a01 += __shfl_xor(a01, o);
            a10 += __shfl_xor(a10, o); a11 += __shfl_xor(a11, o);
        }
        if (lane == 0) {   // subtract exact identity contribution
            gout[r0] = a00 - sgf[r0];
            hout[r0] = a01 - shf[r0];
            gout[r1] = a10 - sgf[r1];
            hout[r1] = a11 - shf[r1];
        }
    }
}

// ---------------- binomial coefficients (fp64) ----------------
__global__ void coeff_kernel(const float* __restrict__ xs,
                             double* __restrict__ s, double* __restrict__ c256)
{
    const int lane = threadIdx.x;        // 64 threads
    const int t0 = lane * 4;
    float xl[8][4];
    #pragma unroll
    for (int b = 0; b < 8; ++b)
        #pragma unroll
        for (int i = 0; i < 4; ++i)
            xl[b][i] = xs[b * 256 + t0 + i];

    double c[4] = {1.0, 1.0, 1.0, 1.0};  // C(255-t, m), m starts at 0
    for (int m = 0; m <= MPOW; ++m) {
        #pragma unroll
        for (int b = 0; b < 8; ++b) {
            double part = c[0] * xl[b][0] + c[1] * xl[b][1]
                        + c[2] * xl[b][2] + c[3] * xl[b][3];
            for (int o = 32; o; o >>= 1) part += __shfl_xor(part, o);
            if (lane == 0) s[m * 8 + b] = part;
        }
        #pragma unroll
        for (int i = 0; i < 4; ++i) {
            double k = (double)(255 - (t0 + i));
            c[i] *= (k - m) / (double)(m + 1);   // -> C(k, m+1); 0 past m=k
        }
    }
    if (lane == 0) {
        double c2 = 1.0;
        for (int m = 0; m <= MPOW; ++m) { c256[m] = c2; c2 = c2 * (256.0 - m) / (double)(m + 1); }
    }
}

// ---------------- combine: p_final[b,i] ----------------
__global__ __launch_bounds__(256)
void combine_kernel(const float* __restrict__ gv, const float* __restrict__ hv,
                    const double* __restrict__ s, const double* __restrict__ c256,
                    float* __restrict__ pfin)
{
    int i = blockIdx.x * 256 + threadIdx.x;
    if (i >= L_) return;
    double acc[8] = {0, 0, 0, 0, 0, 0, 0, 0};
    double hs = 0.0;
    for (int m = 0; m <= MPOW; ++m) {
        double g = (double)gv[(size_t)m * L_ + i];
        double h = (double)hv[(size_t)m * L_ + i];
        hs += c256[m] * h;
        #pragma unroll
        for (int b = 0; b < 8; ++b) acc[b] += s[m * 8 + b] * g;
    }
    #pragma unroll
    for (int b = 0; b < 8; ++b)
        pfin[(size_t)b * L_ + i] = (float)(acc[b] + hs);
}

// ---------------- MLP evaluation ----------------
// weights p: W1[0:64] b1[64:128] W2[128:4224] b2[4224:4288]
//            W3[4288:8384] b3[8384:8448] W4[8448:8832] b4[8832:8838]
__global__ __launch_bounds__(64)
void mlp_kernel(const float* __restrict__ pfin, const float* __restrict__ ts,
                float* __restrict__ out)
{
    const int b = blockIdx.x;
    const int t = blockIdx.y * 64 + threadIdx.x;
    const float* __restrict__ p = pfin + (size_t)b * L_;   // uniform -> s_loads
    const float tv = ts[b * 256 + t];

    float h1[64], h2[64];
    #pragma unroll
    for (int o = 0; o < 64; ++o)
        h1[o] = fmaxf(fmaf(p[o], tv, p[64 + o]), 0.f);
    #pragma unroll
    for (int o = 0; o < 64; ++o) {
        float a0 = p[4224 + o], a1 = 0.f, a2 = 0.f, a3 = 0.f;
        #pragma unroll
        for (int d = 0; d < 64; d += 4) {
            a0 = fmaf(p[128 + o * 64 + d + 0], h1[d + 0], a0);
            a1 = fmaf(p[128 + o * 64 + d + 1], h1[d + 1], a1);
            a2 = fmaf(p[128 + o * 64 + d + 2], h1[d + 2], a2);
            a3 = fmaf(p[128 + o * 64 + d + 3], h1[d + 3], a3);
        }
        h2[o] = fmaxf((a0 + a1) + (a2 + a3), 0.f);
    }
    #pragma unroll
    for (int o = 0; o < 64; ++o) {
        float a0 = p[8384 + o], a1 = 0.f, a2 = 0.f, a3 = 0.f;
        #pragma unroll
        for (int d = 0; d < 64; d += 4) {
            a0 = fmaf(p[4288 + o * 64 + d + 0], h2[d + 0], a0);
            a1 = fmaf(p[4288 + o * 64 + d + 1], h2[d + 1], a1);
            a2 = fmaf(p[4288 + o * 64 + d + 2], h2[d + 2], a2);
            a3 = fmaf(p[4288 + o * 64 + d + 3], h2[d + 3], a3);
        }
        h1[o] = fmaxf((a0 + a1) + (a2 + a3), 0.f);   // reuse as h3
    }
    #pragma unroll
    for (int o = 0; o < 6; ++o) {
        float a0 = p[8832 + o], a1 = 0.f, a2 = 0.f, a3 = 0.f;
        #pragma unroll
        for (int d = 0; d < 64; d += 4) {
            a0 = fmaf(p[8448 + o * 64 + d + 0], h1[d + 0], a0);
            a1 = fmaf(p[8448 + o * 64 + d + 1], h1[d + 1], a1);
            a2 = fmaf(p[8448 + o * 64 + d + 2], h1[d + 2], a2);
            a3 = fmaf(p[8448 + o * 64 + d + 3], h1[d + 3], a3);
        }
        out[((size_t)(b * 256 + t)) * 6 + o] = (a0 + a1) + (a2 + a3);
    }
}

// ---------------- host launcher ----------------
extern "C" void kernel_launch(void* const* d_in, const int* in_sizes, int n_in,
                              void* d_out, int out_size, void* d_ws, size_t ws_size,
                              hipStream_t stream)
{
    const float* xs    = (const float*)d_in[0];  // (8,1,256,1)
    const float* ts    = (const float*)d_in[1];  // (8,256)
    const float* theta = (const float*)d_in[2];  // (8838,)
    const float* A     = (const float*)d_in[3];  // (8838,8838)
    const float* B     = (const float*)d_in[4];  // (8838,1)
    float* out = (float*)d_out;

    const size_t GB1 = (size_t)L_ * LP_;                          // 81,451,008 per array
    const size_t VB  = (size_t)NSLOT * L_ * sizeof(float);
    const size_t SB  = (size_t)NSLOT * 8 * sizeof(double);
    const size_t CB  = 256;                                       // c256 (padded)
    const size_t PB  = (size_t)8 * L_ * sizeof(float);
    const size_t SMALL = 2 * VB + SB + CB + PB;
    const size_t FULL  = 2 * GB1 + SMALL;

    if (ws_size < SMALL) return;   // cannot run; fail loudly via validation
    const bool fat = (ws_size >= FULL);

    char* base = (char*)d_ws;
    unsigned char* GHi = (unsigned char*)base;
    unsigned char* GLo = (unsigned char*)(base + GB1);
    size_t off = fat ? 2 * GB1 : 0;
    float*  gv   = (float*)(base + off);  off += VB;
    float*  hv   = (float*)(base + off);  off += VB;
    double* s    = (double*)(base + off); off += SB;
    double* c256 = (double*)(base + off); off += CB;
    float*  pfin = (float*)(base + off);

    // independent of chain -> launch first
    coeff_kernel<<<1, 64, 0, stream>>>(xs, s, c256);

    // slot 0: g_0 = B, h_0 = theta (exact fp32)
    hipMemcpyAsync(gv, B,     L_ * sizeof(float), hipMemcpyDeviceToDevice, stream);
    hipMemcpyAsync(hv, theta, L_ * sizeof(float), hipMemcpyDeviceToDevice, stream);

    if (fat) {
        // pass 0: fp32 A (nt), exact slot1, fused hi/lo quantized G write
        chain_fp32<true><<<dim3(CWGRID), dim3(CT), 0, stream>>>(
            A, gv, hv, GHi, GLo, gv + L_, hv + L_);
        for (int p = 1; p < MPOW; ++p) {
            const float* gi = gv + (size_t)p * L_;
            const float* hi = hv + (size_t)p * L_;
            float* go = gv + (size_t)(p + 1) * L_;
            float* ho = hv + (size_t)(p + 1) * L_;
            if (p <= NFULL)
                chain_full<<<dim3(CWGRID), dim3(CT), 0, stream>>>(GHi, GLo, gi, hi, go, ho);
            else
                chain_hi<<<dim3(CWGRID), dim3(CT), 0, stream>>>(GHi, gi, hi, go, ho);
        }
    } else {
        for (int p = 0; p < MPOW; ++p)
            chain_fp32<false><<<dim3(CWGRID), dim3(CT), 0, stream>>>(A,
                gv + (size_t)p * L_,       hv + (size_t)p * L_,
                nullptr, nullptr,
                gv + (size_t)(p + 1) * L_, hv + (size_t)(p + 1) * L_);
    }

    combine_kernel<<<(L_ + 255) / 256, 256, 0, stream>>>(gv, hv, s, c256, pfin);
    mlp_kernel<<<dim3(8, 4), 64, 0, stream>>>(pfin, ts, out);
}